// Round 1
// baseline (617.576 us; speedup 1.0000x reference)
//
#include <hip/hip_runtime.h>
#include <hip/hip_bf16.h>

typedef __bf16 bf16x8 __attribute__((ext_vector_type(8)));
typedef float f32x4 __attribute__((ext_vector_type(4)));

#define MFMA16x16(a, b, c) __builtin_amdgcn_mfma_f32_16x16x32_bf16((a), (b), (c), 0, 0, 0)

namespace {
constexpr int BATCH = 8;
constexpr int DIMC  = 256;   // input/output channel dim
constexpr int WLEN  = 2048;  // sequence length
constexpr int DH    = 64;
constexpr int HID   = 512;   // heads * dh
// fold softmax scale and log2(e) into q so we can use exp2f exactly:
// exp2(log2e*s - log2e*m) == e^(s-m)
constexpr float QSCALE = 0.125f * 1.44269504088896340736f;

// workspace byte offsets
constexpr size_t OFF_WQKV = 0;          // 1536*256*2      =   786432
constexpr size_t OFF_WOUT = 786432;     // 256*512*2       =   262144
constexpr size_t OFF_XT   = 1048576;    // 8*2048*256*2    =  8388608
constexpr size_t OFF_QKT  = 9437184;    // 8*2048*1024*2   = 33554432
constexpr size_t OFF_V    = 42991616;   // 8*512*2048*2    = 16777216
constexpr size_t OFF_AT   = 59768832;   // 8*2048*512*2    = 16777216
}                                        // total ~73 MB

// ---- kernel 1: weights f32 -> bf16 ----------------------------------------
__global__ __launch_bounds__(256) void prep_weights(
    const float* __restrict__ wqkv, const float* __restrict__ wout,
    __hip_bfloat16* __restrict__ wqkv_bf, __hip_bfloat16* __restrict__ wout_bf) {
  int i = blockIdx.x * 256 + threadIdx.x;
  if (i < 1536 * 256) wqkv_bf[i] = __float2bfloat16(wqkv[i]);
  if (i < 256 * 512)  wout_bf[i] = __float2bfloat16(wout[i]);
}

// ---- kernel 2: x [b][256][2048] f32 -> xT [b][2048][256] bf16 --------------
__global__ __launch_bounds__(256) void transpose_x(
    const float* __restrict__ x, __hip_bfloat16* __restrict__ xT) {
  __shared__ float t[64][65];
  int b = blockIdx.z;
  int d0 = blockIdx.y * 64, w0 = blockIdx.x * 64;
  int tid = threadIdx.x;
  const float* xb = x + (size_t)b * DIMC * WLEN;
#pragma unroll
  for (int r = 0; r < 16; ++r) {
    int dd = r * 4 + (tid >> 6);
    int ww = tid & 63;
    t[dd][ww] = xb[(size_t)(d0 + dd) * WLEN + w0 + ww];
  }
  __syncthreads();
  __hip_bfloat16* xTb = xT + (size_t)b * WLEN * DIMC;
#pragma unroll
  for (int r = 0; r < 16; ++r) {
    int ww = r * 4 + (tid >> 6);
    int dd = tid & 63;
    xTb[(size_t)(w0 + ww) * DIMC + d0 + dd] = __float2bfloat16(t[dd][ww]);
  }
}

// ---- kernel 3: qkv GEMM: C[o][w] = sum_d wqkv[o][d] * x[d][w] ---------------
// q,k (o<1024) stored transposed into qkT[b][w][o] (q pre-scaled);
// v (o>=1024) stored natural into vbuf[b][o-1024][w]
__global__ __launch_bounds__(256) void qkv_gemm(
    const __hip_bfloat16* __restrict__ wqkv_bf,
    const __hip_bfloat16* __restrict__ xT,
    __hip_bfloat16* __restrict__ qkT, __hip_bfloat16* __restrict__ vbuf) {
  int b = blockIdx.z;
  int bo = blockIdx.y * 64, bw = blockIdx.x * 64;
  int tid = threadIdx.x;
  int wid = tid >> 6, lane = tid & 63;
  int g = lane >> 4, r16 = lane & 15;

  const __hip_bfloat16* Arow = wqkv_bf + (size_t)(bo + wid * 16 + r16) * DIMC;
  const __hip_bfloat16* Bb = xT + (size_t)b * WLEN * DIMC;

  f32x4 acc[4];
#pragma unroll
  for (int t = 0; t < 4; ++t) acc[t] = f32x4{0.f, 0.f, 0.f, 0.f};

  for (int kk = 0; kk < 8; ++kk) {
    int kb = kk * 32 + g * 8;
    bf16x8 a = *reinterpret_cast<const bf16x8*>(Arow + kb);
#pragma unroll
    for (int t = 0; t < 4; ++t) {
      bf16x8 bb = *reinterpret_cast<const bf16x8*>(
          Bb + (size_t)(bw + t * 16 + r16) * DIMC + kb);
      acc[t] = MFMA16x16(a, bb, acc[t]);
    }
  }

  __shared__ float C[64][65];
#pragma unroll
  for (int t = 0; t < 4; ++t)
#pragma unroll
    for (int r = 0; r < 4; ++r)
      C[wid * 16 + g * 4 + r][t * 16 + r16] = acc[t][r];
  __syncthreads();

  if (bo < 1024) {  // q or k -> transposed store
    __hip_bfloat16* out = qkT + (size_t)b * WLEN * 1024;
#pragma unroll
    for (int it = 0; it < 16; ++it) {
      int idx = it * 256 + tid;
      int wl = idx >> 6, ol = idx & 63;
      float v = C[ol][wl];
      if (bo + ol < 512) v *= QSCALE;
      out[(size_t)(bw + wl) * 1024 + bo + ol] = __float2bfloat16(v);
    }
  } else {  // v -> natural store
    __hip_bfloat16* out = vbuf + (size_t)b * HID * WLEN;
#pragma unroll
    for (int it = 0; it < 16; ++it) {
      int idx = it * 256 + tid;
      int ol = idx >> 6, wl = idx & 63;
      out[(size_t)(bo - 1024 + ol) * WLEN + bw + wl] = __float2bfloat16(C[ol][wl]);
    }
  }
}

// ---- kernel 4: flash attention ---------------------------------------------
// per block: one (b,h), 64 q rows (16 per wave). online softmax in exp2 domain.
__global__ __launch_bounds__(256) void attn_kernel(
    const __hip_bfloat16* __restrict__ qkT,
    const __hip_bfloat16* __restrict__ vbuf,
    __hip_bfloat16* __restrict__ attnT) {
  int bh = blockIdx.y;
  int b = bh >> 3, h = bh & 7;
  int i0 = blockIdx.x * 64;
  int tid = threadIdx.x, wid = tid >> 6, lane = tid & 63;
  int g = lane >> 4, r16 = lane & 15;

  const __hip_bfloat16* qk_b = qkT + (size_t)b * WLEN * 1024;
  const __hip_bfloat16* vb = vbuf + (size_t)b * HID * WLEN + (size_t)h * DH * WLEN;

  // Q fragments (held for whole KV loop); q is pre-scaled by QSCALE
  int i_row = i0 + wid * 16 + r16;
  bf16x8 aQ0 = *reinterpret_cast<const bf16x8*>(qk_b + (size_t)i_row * 1024 + h * 64 + g * 8);
  bf16x8 aQ1 = *reinterpret_cast<const bf16x8*>(qk_b + (size_t)i_row * 1024 + h * 64 + 32 + g * 8);

  float m[4], l[4];
  f32x4 o[4];
#pragma unroll
  for (int r = 0; r < 4; ++r) { m[r] = -1e30f; l[r] = 0.f; }
#pragma unroll
  for (int dt = 0; dt < 4; ++dt) o[dt] = f32x4{0.f, 0.f, 0.f, 0.f};

  __shared__ __align__(16) __hip_bfloat16 p_lds[4][16][72];
  __shared__ float O_lds[64][65];

  for (int j0 = 0; j0 < WLEN; j0 += 64) {
    // S^ tiles: S[i][j] over 4 j-subtiles of 16, K-dim d=64 (2 chained mfma)
    f32x4 s[4];
#pragma unroll
    for (int t = 0; t < 4; ++t) {
      const __hip_bfloat16* krow = qk_b + (size_t)(j0 + t * 16 + r16) * 1024 + 512 + h * 64;
      bf16x8 k0 = *reinterpret_cast<const bf16x8*>(krow + g * 8);
      bf16x8 k1 = *reinterpret_cast<const bf16x8*>(krow + 32 + g * 8);
      f32x4 z = f32x4{0.f, 0.f, 0.f, 0.f};
      z = MFMA16x16(aQ0, k0, z);
      s[t] = MFMA16x16(aQ1, k1, z);
    }
    // online softmax update; row i = 4g+r lives across lanes sharing (lane>>4)
#pragma unroll
    for (int r = 0; r < 4; ++r) {
      float vm = fmaxf(fmaxf(s[0][r], s[1][r]), fmaxf(s[2][r], s[3][r]));
#pragma unroll
      for (int msk = 1; msk < 16; msk <<= 1) vm = fmaxf(vm, __shfl_xor(vm, msk));
      float mn = fmaxf(m[r], vm);
      float al = exp2f(m[r] - mn);
      float rs = 0.f;
#pragma unroll
      for (int t = 0; t < 4; ++t) {
        float p = exp2f(s[t][r] - mn);
        s[t][r] = p;
        rs += p;
      }
#pragma unroll
      for (int msk = 1; msk < 16; msk <<= 1) rs += __shfl_xor(rs, msk);
      l[r] = l[r] * al + rs;
      m[r] = mn;
#pragma unroll
      for (int dt = 0; dt < 4; ++dt) o[dt][r] *= al;
    }
    // P -> per-wave LDS tile (transpose across lanes for PV A-fragment)
#pragma unroll
    for (int t = 0; t < 4; ++t)
#pragma unroll
      for (int r = 0; r < 4; ++r)
        p_lds[wid][g * 4 + r][t * 16 + r16] = __float2bfloat16(s[t][r]);
    // PV: out[i][d] += P[i][j] * V[d][j]
#pragma unroll
    for (int c = 0; c < 2; ++c) {
      bf16x8 pa = *reinterpret_cast<const bf16x8*>(&p_lds[wid][r16][c * 32 + g * 8]);
#pragma unroll
      for (int dt = 0; dt < 4; ++dt) {
        bf16x8 bv = *reinterpret_cast<const bf16x8*>(
            vb + (size_t)(dt * 16 + r16) * WLEN + j0 + c * 32 + g * 8);
        o[dt] = MFMA16x16(pa, bv, o[dt]);
      }
    }
  }

  // normalize, bounce through LDS, coalesced store attnT[b][i][h*64+d]
#pragma unroll
  for (int dt = 0; dt < 4; ++dt)
#pragma unroll
    for (int r = 0; r < 4; ++r)
      O_lds[wid * 16 + g * 4 + r][dt * 16 + r16] = o[dt][r] / l[r];
  __syncthreads();
  __hip_bfloat16* ob = attnT + (size_t)b * WLEN * HID;
#pragma unroll
  for (int it = 0; it < 16; ++it) {
    int idx = it * 256 + tid;
    int il = idx >> 6, dl = idx & 63;
    ob[(size_t)(i0 + il) * HID + h * 64 + dl] = __float2bfloat16(O_lds[il][dl]);
  }
}

// ---- kernel 5: output projection: out[b][o][i] = sum_c wout[o][c]*attnT[i][c] + b_out[o]
__global__ __launch_bounds__(256) void out_proj(
    const __hip_bfloat16* __restrict__ attnT,
    const __hip_bfloat16* __restrict__ wout_bf,
    const float* __restrict__ b_out, float* __restrict__ out) {
  int b = blockIdx.z;
  int bo = blockIdx.y * 64;
  int bi = blockIdx.x * 64;
  int tid = threadIdx.x, wid = tid >> 6, lane = tid & 63;
  int g = lane >> 4, r16 = lane & 15;

  const __hip_bfloat16* Ab = attnT + (size_t)b * WLEN * HID + (size_t)(bi + wid * 16 + r16) * HID;
  f32x4 acc[4];
#pragma unroll
  for (int t = 0; t < 4; ++t) acc[t] = f32x4{0.f, 0.f, 0.f, 0.f};

  for (int kk = 0; kk < 16; ++kk) {
    int kb = kk * 32 + g * 8;
    bf16x8 a = *reinterpret_cast<const bf16x8*>(Ab + kb);
#pragma unroll
    for (int t = 0; t < 4; ++t) {
      bf16x8 bw = *reinterpret_cast<const bf16x8*>(
          wout_bf + (size_t)(bo + t * 16 + r16) * HID + kb);
      acc[t] = MFMA16x16(a, bw, acc[t]);
    }
  }

  float* outb = out + (size_t)b * DIMC * WLEN;
#pragma unroll
  for (int t = 0; t < 4; ++t) {
    int oc = bo + t * 16 + r16;
    float bias = b_out[oc];
    f32x4 v;
#pragma unroll
    for (int r = 0; r < 4; ++r) v[r] = acc[t][r] + bias;
    *reinterpret_cast<f32x4*>(outb + (size_t)oc * WLEN + bi + wid * 16 + g * 4) = v;
  }
}

extern "C" void kernel_launch(void* const* d_in, const int* in_sizes, int n_in,
                              void* d_out, int out_size, void* d_ws, size_t ws_size,
                              hipStream_t stream) {
  const float* x    = (const float*)d_in[0];
  const float* wqkv = (const float*)d_in[1];
  const float* wout = (const float*)d_in[2];
  const float* bout = (const float*)d_in[3];
  float* out = (float*)d_out;
  char* ws = (char*)d_ws;

  __hip_bfloat16* wqkv_bf = (__hip_bfloat16*)(ws + OFF_WQKV);
  __hip_bfloat16* wout_bf = (__hip_bfloat16*)(ws + OFF_WOUT);
  __hip_bfloat16* xT      = (__hip_bfloat16*)(ws + OFF_XT);
  __hip_bfloat16* qkT     = (__hip_bfloat16*)(ws + OFF_QKT);
  __hip_bfloat16* vbuf    = (__hip_bfloat16*)(ws + OFF_V);
  __hip_bfloat16* attnT   = (__hip_bfloat16*)(ws + OFF_AT);

  prep_weights<<<dim3(1536), dim3(256), 0, stream>>>(wqkv, wout, wqkv_bf, wout_bf);
  transpose_x<<<dim3(WLEN / 64, DIMC / 64, BATCH), dim3(256), 0, stream>>>(x, xT);
  qkv_gemm<<<dim3(WLEN / 64, 1536 / 64, BATCH), dim3(256), 0, stream>>>(wqkv_bf, xT, qkT, vbuf);
  attn_kernel<<<dim3(WLEN / 64, 64), dim3(256), 0, stream>>>(qkT, vbuf, attnT);
  out_proj<<<dim3(WLEN / 64, DIMC / 64, BATCH), dim3(256), 0, stream>>>(attnT, wout_bf, bout, out);
}

// Round 2
// 396.166 us; speedup vs baseline: 1.5589x; 1.5589x over previous
//
#include <hip/hip_runtime.h>
#include <hip/hip_bf16.h>

typedef __bf16 bf16x8 __attribute__((ext_vector_type(8)));
typedef float f32x4 __attribute__((ext_vector_type(4)));
typedef float f32x16 __attribute__((ext_vector_type(16)));

#define MFMA16x16(a, b, c) __builtin_amdgcn_mfma_f32_16x16x32_bf16((a), (b), (c), 0, 0, 0)
#define MFMA32x32(a, b, c) __builtin_amdgcn_mfma_f32_32x32x16_bf16((a), (b), (c), 0, 0, 0)

namespace {
constexpr int BATCH = 8;
constexpr int DIMC  = 256;   // input/output channel dim
constexpr int WLEN  = 2048;  // sequence length
constexpr int DH    = 64;
constexpr int HID   = 512;   // heads * dh
// fold softmax scale and log2(e) into q so we can use exp2f exactly:
// exp2(log2e*s - log2e*m) == e^(s-m)
constexpr float QSCALE = 0.125f * 1.44269504088896340736f;

// workspace byte offsets
constexpr size_t OFF_WQKV = 0;          // 1536*256*2      =   786432
constexpr size_t OFF_WOUT = 786432;     // 256*512*2       =   262144
constexpr size_t OFF_XT   = 1048576;    // 8*2048*256*2    =  8388608
constexpr size_t OFF_QKT  = 9437184;    // 8*2048*1024*2   = 33554432
constexpr size_t OFF_V    = 42991616;   // 8*512*2048*2    = 16777216
constexpr size_t OFF_AT   = 59768832;   // 8*2048*512*2    = 16777216
}                                        // total ~73 MB

__device__ inline unsigned cvt_pk_bf16(float a, float b) {
  unsigned r;
  asm("v_cvt_pk_bf16_f32 %0, %1, %2" : "=v"(r) : "v"(a), "v"(b));
  return r;
}

// ---- kernel 1: weights f32 -> bf16 ----------------------------------------
__global__ __launch_bounds__(256) void prep_weights(
    const float* __restrict__ wqkv, const float* __restrict__ wout,
    __hip_bfloat16* __restrict__ wqkv_bf, __hip_bfloat16* __restrict__ wout_bf) {
  int i = blockIdx.x * 256 + threadIdx.x;
  if (i < 1536 * 256) wqkv_bf[i] = __float2bfloat16(wqkv[i]);
  if (i < 256 * 512)  wout_bf[i] = __float2bfloat16(wout[i]);
}

// ---- kernel 2: x [b][256][2048] f32 -> xT [b][2048][256] bf16 --------------
__global__ __launch_bounds__(256) void transpose_x(
    const float* __restrict__ x, __hip_bfloat16* __restrict__ xT) {
  __shared__ float t[64][65];
  int b = blockIdx.z;
  int d0 = blockIdx.y * 64, w0 = blockIdx.x * 64;
  int tid = threadIdx.x;
  const float* xb = x + (size_t)b * DIMC * WLEN;
#pragma unroll
  for (int r = 0; r < 16; ++r) {
    int dd = r * 4 + (tid >> 6);
    int ww = tid & 63;
    t[dd][ww] = xb[(size_t)(d0 + dd) * WLEN + w0 + ww];
  }
  __syncthreads();
  __hip_bfloat16* xTb = xT + (size_t)b * WLEN * DIMC;
#pragma unroll
  for (int r = 0; r < 16; ++r) {
    int ww = r * 4 + (tid >> 6);
    int dd = tid & 63;
    xTb[(size_t)(w0 + ww) * DIMC + d0 + dd] = __float2bfloat16(t[dd][ww]);
  }
}

// ---- kernel 3: qkv GEMM: C[o][w] = sum_d wqkv[o][d] * x[d][w] ---------------
// q,k (o<1024) stored transposed into qkT[b][w][o] (q pre-scaled);
// v (o>=1024) stored natural into vbuf[b][o-1024][w]
__global__ __launch_bounds__(256) void qkv_gemm(
    const __hip_bfloat16* __restrict__ wqkv_bf,
    const __hip_bfloat16* __restrict__ xT,
    __hip_bfloat16* __restrict__ qkT, __hip_bfloat16* __restrict__ vbuf) {
  int b = blockIdx.z;
  int bo = blockIdx.y * 64, bw = blockIdx.x * 64;
  int tid = threadIdx.x;
  int wid = tid >> 6, lane = tid & 63;
  int g = lane >> 4, r16 = lane & 15;

  const __hip_bfloat16* Arow = wqkv_bf + (size_t)(bo + wid * 16 + r16) * DIMC;
  const __hip_bfloat16* Bb = xT + (size_t)b * WLEN * DIMC;

  f32x4 acc[4];
#pragma unroll
  for (int t = 0; t < 4; ++t) acc[t] = f32x4{0.f, 0.f, 0.f, 0.f};

  for (int kk = 0; kk < 8; ++kk) {
    int kb = kk * 32 + g * 8;
    bf16x8 a = *reinterpret_cast<const bf16x8*>(Arow + kb);
#pragma unroll
    for (int t = 0; t < 4; ++t) {
      bf16x8 bb = *reinterpret_cast<const bf16x8*>(
          Bb + (size_t)(bw + t * 16 + r16) * DIMC + kb);
      acc[t] = MFMA16x16(a, bb, acc[t]);
    }
  }

  __shared__ float C[64][65];
#pragma unroll
  for (int t = 0; t < 4; ++t)
#pragma unroll
    for (int r = 0; r < 4; ++r)
      C[wid * 16 + g * 4 + r][t * 16 + r16] = acc[t][r];
  __syncthreads();

  if (bo < 1024) {  // q or k -> transposed store
    __hip_bfloat16* out = qkT + (size_t)b * WLEN * 1024;
#pragma unroll
    for (int it = 0; it < 16; ++it) {
      int idx = it * 256 + tid;
      int wl = idx >> 6, ol = idx & 63;
      float v = C[ol][wl];
      if (bo + ol < 512) v *= QSCALE;
      out[(size_t)(bw + wl) * 1024 + bo + ol] = __float2bfloat16(v);
    }
  } else {  // v -> natural store
    __hip_bfloat16* out = vbuf + (size_t)b * HID * WLEN;
#pragma unroll
    for (int it = 0; it < 16; ++it) {
      int idx = it * 256 + tid;
      int ol = idx >> 6, wl = idx & 63;
      out[(size_t)(bo - 1024 + ol) * WLEN + bw + wl] = __float2bfloat16(C[ol][wl]);
    }
  }
}

// ---- kernel 4: flash attention, swapped-operand 32x32 MFMA ------------------
// 4 independent waves/block, 32 q-rows per wave, KVBLK=64 (two 32x32 S-tiles).
// S^T = K·Q^T  (lane owns q-row i = lane&31 => in-register softmax)
// O^T = V^T·P^T (rescale factor lane-local)
__global__ __launch_bounds__(256) void attn_kernel(
    const __hip_bfloat16* __restrict__ qkT,
    const __hip_bfloat16* __restrict__ vbuf,
    __hip_bfloat16* __restrict__ attnT) {
  int bh = blockIdx.y;
  int b = bh >> 3, h = bh & 7;
  int tid = threadIdx.x, wid = tid >> 6, lane = tid & 63;
  int il = lane & 31, hi = lane >> 5;
  int i0w = blockIdx.x * 128 + wid * 32;

  const __hip_bfloat16* qk_b = qkT + (size_t)b * WLEN * 1024;
  const __hip_bfloat16* vb = vbuf + (size_t)b * HID * WLEN + (size_t)h * DH * WLEN;

  // Q fragments (B-operand): col i = il, k = d = s*16 + hi*8 + e  (pre-scaled)
  bf16x8 qf[4];
  {
    const __hip_bfloat16* qrow = qk_b + (size_t)(i0w + il) * 1024 + h * 64 + hi * 8;
#pragma unroll
    for (int s = 0; s < 4; ++s)
      qf[s] = *reinterpret_cast<const bf16x8*>(qrow + s * 16);
  }

  f32x16 oacc0, oacc1;
#pragma unroll
  for (int r = 0; r < 16; ++r) { oacc0[r] = 0.f; oacc1[r] = 0.f; }
  float m = -1e30f, l = 0.f;

  // K fragments (A-operand): row j = t*32 + il, k = d = s*16 + hi*8 + e
  bf16x8 kc[8];
  {
    const __hip_bfloat16* krow = qk_b + (size_t)il * 1024 + 512 + h * 64 + hi * 8;
#pragma unroll
    for (int s = 0; s < 4; ++s) {
      kc[s]     = *reinterpret_cast<const bf16x8*>(krow + s * 16);
      kc[4 + s] = *reinterpret_cast<const bf16x8*>(krow + 32 * 1024 + s * 16);
    }
  }

  for (int j0 = 0; j0 < WLEN; j0 += 64) {
    // prefetch next K tile
    bf16x8 kn[8];
    {
      int jn = (j0 + 64 < WLEN) ? (j0 + 64) : j0;
      const __hip_bfloat16* krow = qk_b + (size_t)(jn + il) * 1024 + 512 + h * 64 + hi * 8;
#pragma unroll
      for (int s = 0; s < 4; ++s) {
        kn[s]     = *reinterpret_cast<const bf16x8*>(krow + s * 16);
        kn[4 + s] = *reinterpret_cast<const bf16x8*>(krow + 32 * 1024 + s * 16);
      }
    }

    // S^T tiles: st0 = rows j0..j0+31, st1 = rows j0+32..j0+63 (cols = q-rows)
    f32x16 st0, st1;
#pragma unroll
    for (int r = 0; r < 16; ++r) { st0[r] = 0.f; st1[r] = 0.f; }
#pragma unroll
    for (int s = 0; s < 4; ++s) {
      st0 = MFMA32x32(kc[s],     qf[s], st0);
      st1 = MFMA32x32(kc[4 + s], qf[s], st1);
    }

    // issue V loads early (A-operand of PV): row d = dt*32 + il, k = j slice
    bf16x8 vf0[4], vf1[4];
    {
      const __hip_bfloat16* vrow = vb + (size_t)il * WLEN + j0 + hi * 8;
#pragma unroll
      for (int js = 0; js < 4; ++js) {
        vf0[js] = *reinterpret_cast<const bf16x8*>(vrow + js * 16);
        vf1[js] = *reinterpret_cast<const bf16x8*>(vrow + 32 * WLEN + js * 16);
      }
    }

    // ---- online softmax, fully in-register (lane owns row i = il) ----------
    float vmax = st0[0];
#pragma unroll
    for (int r = 1; r < 16; ++r) vmax = fmaxf(vmax, st0[r]);
#pragma unroll
    for (int r = 0; r < 16; ++r) vmax = fmaxf(vmax, st1[r]);
    vmax = fmaxf(vmax, __shfl_xor(vmax, 32));
    if (!__all(vmax - m <= 8.0f)) {       // T13 defer-max (exp2 domain)
      float mn = fmaxf(m, vmax);
      float al = exp2f(m - mn);
#pragma unroll
      for (int r = 0; r < 16; ++r) { oacc0[r] *= al; oacc1[r] *= al; }
      l *= al;
      m = mn;
    }
    float rs = 0.f;
#pragma unroll
    for (int r = 0; r < 16; ++r) { float p = exp2f(st0[r] - m); st0[r] = p; rs += p; }
#pragma unroll
    for (int r = 0; r < 16; ++r) { float p = exp2f(st1[r] - m); st1[r] = p; rs += p; }
    rs += __shfl_xor(rs, 32);
    l += rs;

    // ---- P^T -> PV B-fragments via cvt_pk + cross-half exchange (T12) ------
    // lane holds P^T[j][i]: j = j0 + t*32 + (reg&3) + 4*hi + 8*(reg>>2), i = il
    // B-frag js needs k-elements j = j0 + js*16 + hi*8 + e (e=0..7)
    unsigned Wv[2][8];
#pragma unroll
    for (int q = 0; q < 8; ++q) {
      Wv[0][q] = cvt_pk_bf16(st0[2 * q], st0[2 * q + 1]);
      Wv[1][q] = cvt_pk_bf16(st1[2 * q], st1[2 * q + 1]);
    }
    bf16x8 pf[4];
#pragma unroll
    for (int t = 0; t < 2; ++t) {
#pragma unroll
      for (int a = 0; a < 2; ++a) {
        unsigned x0 = Wv[t][4 * a + 0], x1 = Wv[t][4 * a + 1];
        unsigned x2 = Wv[t][4 * a + 2], x3 = Wv[t][4 * a + 3];
        unsigned y0 = (unsigned)__shfl_xor((int)x0, 32);
        unsigned y1 = (unsigned)__shfl_xor((int)x1, 32);
        unsigned y2 = (unsigned)__shfl_xor((int)x2, 32);
        unsigned y3 = (unsigned)__shfl_xor((int)x3, 32);
        union { unsigned u[4]; bf16x8 v; } pk;
        pk.u[0] = hi ? y2 : x0;
        pk.u[1] = hi ? y3 : x1;
        pk.u[2] = hi ? x2 : y0;
        pk.u[3] = hi ? x3 : y1;
        pf[t * 2 + a] = pk.v;
      }
    }

    // ---- PV: O^T[d][i] += V^T[d][j] * P^T[j][i] ----------------------------
#pragma unroll
    for (int js = 0; js < 4; ++js) oacc0 = MFMA32x32(vf0[js], pf[js], oacc0);
#pragma unroll
    for (int js = 0; js < 4; ++js) oacc1 = MFMA32x32(vf1[js], pf[js], oacc1);

#pragma unroll
    for (int r = 0; r < 8; ++r) kc[r] = kn[r];
  }

  // ---- epilogue: normalize, per-wave LDS bounce, coalesced bf16x8 stores ---
  __shared__ __hip_bfloat16 olds[4][32][72];
  float rl = 1.0f / l;
#pragma unroll
  for (int q = 0; q < 8; ++q) {
    int dl = ((2 * q) & 3) + 8 * (q >> 1) + 4 * hi;  // even pair base
    unsigned pk0 = cvt_pk_bf16(oacc0[2 * q] * rl, oacc0[2 * q + 1] * rl);
    unsigned pk1 = cvt_pk_bf16(oacc1[2 * q] * rl, oacc1[2 * q + 1] * rl);
    *reinterpret_cast<unsigned*>(&olds[wid][il][dl])      = pk0;
    *reinterpret_cast<unsigned*>(&olds[wid][il][32 + dl]) = pk1;
  }
  // per-wave tile: compiler orders LDS write->read via lgkmcnt; no barrier.
  __hip_bfloat16* ob = attnT + (size_t)b * WLEN * HID + h * 64;
  int dcol = (lane & 7) * 8;
#pragma unroll
  for (int it = 0; it < 4; ++it) {
    int ir = it * 8 + (lane >> 3);
    bf16x8 vrow = *reinterpret_cast<const bf16x8*>(&olds[wid][ir][dcol]);
    *reinterpret_cast<bf16x8*>(ob + (size_t)(i0w + ir) * HID + dcol) = vrow;
  }
}

// ---- kernel 5: output projection: out[b][o][i] = sum_c wout[o][c]*attnT[i][c] + b_out[o]
__global__ __launch_bounds__(256) void out_proj(
    const __hip_bfloat16* __restrict__ attnT,
    const __hip_bfloat16* __restrict__ wout_bf,
    const float* __restrict__ b_out, float* __restrict__ out) {
  int b = blockIdx.z;
  int bo = blockIdx.y * 64;
  int bi = blockIdx.x * 64;
  int tid = threadIdx.x, wid = tid >> 6, lane = tid & 63;
  int g = lane >> 4, r16 = lane & 15;

  const __hip_bfloat16* Ab = attnT + (size_t)b * WLEN * HID + (size_t)(bi + wid * 16 + r16) * HID;
  f32x4 acc[4];
#pragma unroll
  for (int t = 0; t < 4; ++t) acc[t] = f32x4{0.f, 0.f, 0.f, 0.f};

  for (int kk = 0; kk < 16; ++kk) {
    int kb = kk * 32 + g * 8;
    bf16x8 a = *reinterpret_cast<const bf16x8*>(Ab + kb);
#pragma unroll
    for (int t = 0; t < 4; ++t) {
      bf16x8 bw = *reinterpret_cast<const bf16x8*>(
          wout_bf + (size_t)(bo + t * 16 + r16) * HID + kb);
      acc[t] = MFMA16x16(a, bw, acc[t]);
    }
  }

  float* outb = out + (size_t)b * DIMC * WLEN;
#pragma unroll
  for (int t = 0; t < 4; ++t) {
    int oc = bo + t * 16 + r16;
    float bias = b_out[oc];
    f32x4 v;
#pragma unroll
    for (int r = 0; r < 4; ++r) v[r] = acc[t][r] + bias;
    *reinterpret_cast<f32x4*>(outb + (size_t)oc * WLEN + bi + wid * 16 + g * 4) = v;
  }
}

extern "C" void kernel_launch(void* const* d_in, const int* in_sizes, int n_in,
                              void* d_out, int out_size, void* d_ws, size_t ws_size,
                              hipStream_t stream) {
  const float* x    = (const float*)d_in[0];
  const float* wqkv = (const float*)d_in[1];
  const float* wout = (const float*)d_in[2];
  const float* bout = (const float*)d_in[3];
  float* out = (float*)d_out;
  char* ws = (char*)d_ws;

  __hip_bfloat16* wqkv_bf = (__hip_bfloat16*)(ws + OFF_WQKV);
  __hip_bfloat16* wout_bf = (__hip_bfloat16*)(ws + OFF_WOUT);
  __hip_bfloat16* xT      = (__hip_bfloat16*)(ws + OFF_XT);
  __hip_bfloat16* qkT     = (__hip_bfloat16*)(ws + OFF_QKT);
  __hip_bfloat16* vbuf    = (__hip_bfloat16*)(ws + OFF_V);
  __hip_bfloat16* attnT   = (__hip_bfloat16*)(ws + OFF_AT);

  prep_weights<<<dim3(1536), dim3(256), 0, stream>>>(wqkv, wout, wqkv_bf, wout_bf);
  transpose_x<<<dim3(WLEN / 64, DIMC / 64, BATCH), dim3(256), 0, stream>>>(x, xT);
  qkv_gemm<<<dim3(WLEN / 64, 1536 / 64, BATCH), dim3(256), 0, stream>>>(wqkv_bf, xT, qkT, vbuf);
  attn_kernel<<<dim3(WLEN / 128, 64), dim3(256), 0, stream>>>(qkT, vbuf, attnT);
  out_proj<<<dim3(WLEN / 64, DIMC / 64, BATCH), dim3(256), 0, stream>>>(attnT, wout_bf, bout, out);
}